// Round 2
// baseline (8497.775 us; speedup 1.0000x reference)
//
#include <hip/hip_runtime.h>
#include <hip/hip_bf16.h>
#include <cstdint>
#include <cstddef>

#define N_NODES 100000
#define N_EDGES 1600000
#define F_IN    256
#define HID     128

__device__ inline float bf16u_to_f32(unsigned short u) {
    return __uint_as_float(((unsigned int)u) << 16);
}
__device__ inline unsigned short f32_to_bf16u(float f) {
    union { __hip_bfloat16 h; unsigned short u; } c;
    c.h = __float2bfloat16(f);
    return c.u;
}

// ---------------- utility ----------------

__global__ __launch_bounds__(256) void zero_kernel(float* __restrict__ p, int n) {
    int i = blockIdx.x * 256 + threadIdx.x;
    if (i < n) p[i] = 0.f;
}

// ---------------- degree / normalization ----------------

__global__ __launch_bounds__(256) void deg_kernel(const int* __restrict__ dst,
                                                  float* __restrict__ deg, int nE) {
    int e = blockIdx.x * 256 + threadIdx.x;
    if (e < nE) atomicAdd(&deg[dst[e]], 1.0f);
}

__global__ __launch_bounds__(256) void dinv_kernel(float* __restrict__ deg, int n) {
    int i = blockIdx.x * 256 + threadIdx.x;
    if (i < n) deg[i] = rsqrtf(deg[i] + 1.0f);   // deg includes self-loop
}

// ---------------- GEMM: Y[N,128] = X[N,K] @ W[K,128] (optional relu on X) ----
// OUT_BF16: store output as bf16 (workspace-constrained fallback path).

template <int K, bool RELU, bool OUT_BF16>
__global__ __launch_bounds__(256) void gemm_kernel(const float* __restrict__ X,
                                                   const float* __restrict__ W,
                                                   void* __restrict__ Yv, int n) {
    __shared__ float4 Wl[4096];            // 128 k-rows x 32 float4 (=128 cols), 64 KB
    const int row = blockIdx.x * 256 + threadIdx.x;

    float acc[HID];
#pragma unroll
    for (int j = 0; j < HID; ++j) acc[j] = 0.f;

    for (int kc = 0; kc < K; kc += 128) {
        __syncthreads();
        const float4* Wg = reinterpret_cast<const float4*>(W + (size_t)kc * HID);
        for (int t = threadIdx.x; t < 4096; t += 256) Wl[t] = Wg[t];
        __syncthreads();

        if (row < n) {
            const float4* xr = reinterpret_cast<const float4*>(X + (size_t)row * K + kc);
            auto fma_step = [&](float xv, int k) {
                const float4* wrow = &Wl[k * 32];
#pragma unroll
                for (int j4 = 0; j4 < 32; ++j4) {
                    float4 w = wrow[j4];
                    acc[j4 * 4 + 0] += xv * w.x;
                    acc[j4 * 4 + 1] += xv * w.y;
                    acc[j4 * 4 + 2] += xv * w.z;
                    acc[j4 * 4 + 3] += xv * w.w;
                }
            };
#pragma unroll 2
            for (int k4 = 0; k4 < 32; ++k4) {
                float4 xq = xr[k4];
                if (RELU) {
                    xq.x = fmaxf(xq.x, 0.f); xq.y = fmaxf(xq.y, 0.f);
                    xq.z = fmaxf(xq.z, 0.f); xq.w = fmaxf(xq.w, 0.f);
                }
                fma_step(xq.x, k4 * 4 + 0);
                fma_step(xq.y, k4 * 4 + 1);
                fma_step(xq.z, k4 * 4 + 2);
                fma_step(xq.w, k4 * 4 + 3);
            }
        }
    }

    if (row < n) {
        if (OUT_BF16) {
            ushort4* yr = reinterpret_cast<ushort4*>((unsigned short*)Yv + (size_t)row * HID);
#pragma unroll
            for (int j4 = 0; j4 < 32; ++j4) {
                ushort4 o;
                o.x = f32_to_bf16u(acc[j4 * 4 + 0]);
                o.y = f32_to_bf16u(acc[j4 * 4 + 1]);
                o.z = f32_to_bf16u(acc[j4 * 4 + 2]);
                o.w = f32_to_bf16u(acc[j4 * 4 + 3]);
                yr[j4] = o;
            }
        } else {
            float4* yr = reinterpret_cast<float4*>((float*)Yv + (size_t)row * HID);
#pragma unroll
            for (int j4 = 0; j4 < 32; ++j4)
                yr[j4] = make_float4(acc[j4 * 4 + 0], acc[j4 * 4 + 1],
                                     acc[j4 * 4 + 2], acc[j4 * 4 + 3]);
        }
    }
}

// ---------------- agg init: agg = xw * dinv^2 + b ----------------

template <bool XW_BF16>
__global__ __launch_bounds__(256) void init_agg_kernel(const void* __restrict__ xwv,
                                                       const float* __restrict__ dinv,
                                                       const float* __restrict__ b,
                                                       float* __restrict__ agg, int n) {
    int i = blockIdx.x * 256 + threadIdx.x;       // over n*32 column-quads
    if (i >= n * 32) return;
    int node = i >> 5;
    int h4   = i & 31;
    float di = dinv[node];
    float s  = di * di;                            // = 1/deg
    float vx, vy, vz, vw;
    if (XW_BF16) {
        ushort4 v = reinterpret_cast<const ushort4*>(xwv)[i];
        vx = bf16u_to_f32(v.x); vy = bf16u_to_f32(v.y);
        vz = bf16u_to_f32(v.z); vw = bf16u_to_f32(v.w);
    } else {
        float4 v = reinterpret_cast<const float4*>(xwv)[i];
        vx = v.x; vy = v.y; vz = v.z; vw = v.w;
    }
    float4 bb = reinterpret_cast<const float4*>(b)[h4];
    float4 r;
    r.x = vx * s + bb.x; r.y = vy * s + bb.y;
    r.z = vz * s + bb.z; r.w = vw * s + bb.w;
    reinterpret_cast<float4*>(agg)[i] = r;
}

// ---------------- edge scatter: agg[dst] += xw[src] * dinv[src]*dinv[dst] ----

template <bool XW_BF16>
__global__ __launch_bounds__(256) void scatter_kernel(const int* __restrict__ srcA,
                                                      const int* __restrict__ dstA,
                                                      const void* __restrict__ xwv,
                                                      const float* __restrict__ dinv,
                                                      float* __restrict__ agg, int nE) {
    int gid = blockIdx.x * 256 + threadIdx.x;      // E*32 = 51.2M < 2^31
    int e = gid >> 5;
    if (e >= nE) return;
    int p = gid & 31;
    int s = srcA[e];
    int d = dstA[e];
    float norm = dinv[s] * dinv[d];
    float vx, vy, vz, vw;
    if (XW_BF16) {
        const unsigned short* xw = (const unsigned short*)xwv;
        ushort4 v = reinterpret_cast<const ushort4*>(xw + (size_t)s * HID)[p];
        vx = bf16u_to_f32(v.x); vy = bf16u_to_f32(v.y);
        vz = bf16u_to_f32(v.z); vw = bf16u_to_f32(v.w);
    } else {
        const float* xw = (const float*)xwv;
        float4 v = reinterpret_cast<const float4*>(xw + (size_t)s * HID)[p];
        vx = v.x; vy = v.y; vz = v.z; vw = v.w;
    }
    float* a = agg + (size_t)d * HID + (size_t)p * 4;
    atomicAdd(a + 0, vx * norm);
    atomicAdd(a + 1, vy * norm);
    atomicAdd(a + 2, vz * norm);
    atomicAdd(a + 3, vw * norm);
}

// ---------------- classifier + log_softmax (relu on input h) ----------------

__global__ __launch_bounds__(256) void classifier_kernel(const float* __restrict__ h,
                                                         const float* __restrict__ Wc,
                                                         const float* __restrict__ bc,
                                                         float* __restrict__ out, int n) {
    __shared__ float wc0[HID], wc1[HID], bcs[2];
    if (threadIdx.x < HID) {
        wc0[threadIdx.x] = Wc[threadIdx.x * 2 + 0];
        wc1[threadIdx.x] = Wc[threadIdx.x * 2 + 1];
    }
    if (threadIdx.x < 2) bcs[threadIdx.x] = bc[threadIdx.x];
    __syncthreads();

    int i = blockIdx.x * 256 + threadIdx.x;
    if (i >= n) return;
    const float4* hr = reinterpret_cast<const float4*>(h + (size_t)i * HID);
    float l0 = 0.f, l1 = 0.f;
#pragma unroll
    for (int j4 = 0; j4 < 32; ++j4) {
        float4 v = hr[j4];
        v.x = fmaxf(v.x, 0.f); v.y = fmaxf(v.y, 0.f);
        v.z = fmaxf(v.z, 0.f); v.w = fmaxf(v.w, 0.f);
        l0 += v.x * wc0[j4 * 4 + 0] + v.y * wc0[j4 * 4 + 1]
            + v.z * wc0[j4 * 4 + 2] + v.w * wc0[j4 * 4 + 3];
        l1 += v.x * wc1[j4 * 4 + 0] + v.y * wc1[j4 * 4 + 1]
            + v.z * wc1[j4 * 4 + 2] + v.w * wc1[j4 * 4 + 3];
    }
    l0 += bcs[0]; l1 += bcs[1];
    float m = fmaxf(l0, l1);
    float lse = m + logf(expf(l0 - m) + expf(l1 - m));
    out[i * 2 + 0] = l0 - lse;
    out[i * 2 + 1] = l1 - lse;
}

// ---------------- launch ----------------

extern "C" void kernel_launch(void* const* d_in, const int* in_sizes, int n_in,
                              void* d_out, int out_size, void* d_ws, size_t ws_size,
                              hipStream_t stream) {
    const float* x   = (const float*)d_in[0];
    const int*   ei  = (const int*)d_in[1];     // harness delivers integers as int32
    const float* W1  = (const float*)d_in[2];
    const float* b1  = (const float*)d_in[3];
    const float* W2  = (const float*)d_in[4];
    const float* b2  = (const float*)d_in[5];
    const float* W3  = (const float*)d_in[6];
    const float* b3  = (const float*)d_in[7];
    const float* Wc  = (const float*)d_in[8];
    const float* bc  = (const float*)d_in[9];
    float*       out = (float*)d_out;

    const int* src = ei;             // edge_index[0,:]
    const int* dst = ei + N_EDGES;   // edge_index[1,:]

    const int nThr = 256;
    const int gN   = (N_NODES + nThr - 1) / nThr;
    const int gE   = (N_EDGES + nThr - 1) / nThr;
    const int gNH4 = (N_NODES * 32 + nThr - 1) / nThr;
    const int gEH4 = (int)(((size_t)N_EDGES * 32 + nThr - 1) / nThr);
    const int gOut = (out_size + nThr - 1) / nThr;

    const size_t dinv_b  = (size_t)N_NODES * 4;
    const size_t nodeF_b = (size_t)N_NODES * HID * 4;   // f32 [N,128]
    const size_t nodeH_b = (size_t)N_NODES * HID * 2;   // bf16 [N,128]
    const size_t need_f32  = dinv_b + 2 * nodeF_b;      // 102.8 MB
    const size_t need_bf16 = dinv_b + nodeH_b + nodeF_b;//  77.2 MB

    if (ws_size >= need_f32) {
        float* dinv = (float*)d_ws;
        float* bufA = (float*)((char*)d_ws + dinv_b);            // xw (f32)
        float* bufB = (float*)((char*)d_ws + dinv_b + nodeF_b);  // agg (f32)

        zero_kernel<<<gN, nThr, 0, stream>>>(dinv, N_NODES);
        deg_kernel<<<gE, nThr, 0, stream>>>(dst, dinv, N_EDGES);
        dinv_kernel<<<gN, nThr, 0, stream>>>(dinv, N_NODES);

        gemm_kernel<F_IN, false, false><<<gN, nThr, 0, stream>>>(x, W1, bufA, N_NODES);
        init_agg_kernel<false><<<gNH4, nThr, 0, stream>>>(bufA, dinv, b1, bufB, N_NODES);
        scatter_kernel<false><<<gEH4, nThr, 0, stream>>>(src, dst, bufA, dinv, bufB, N_EDGES);

        gemm_kernel<HID, true, false><<<gN, nThr, 0, stream>>>(bufB, W2, bufA, N_NODES);
        init_agg_kernel<false><<<gNH4, nThr, 0, stream>>>(bufA, dinv, b2, bufB, N_NODES);
        scatter_kernel<false><<<gEH4, nThr, 0, stream>>>(src, dst, bufA, dinv, bufB, N_EDGES);

        gemm_kernel<HID, true, false><<<gN, nThr, 0, stream>>>(bufB, W3, bufA, N_NODES);
        init_agg_kernel<false><<<gNH4, nThr, 0, stream>>>(bufA, dinv, b3, bufB, N_NODES);
        scatter_kernel<false><<<gEH4, nThr, 0, stream>>>(src, dst, bufA, dinv, bufB, N_EDGES);

        classifier_kernel<<<gN, nThr, 0, stream>>>(bufB, Wc, bc, out, N_NODES);
    } else if (ws_size >= need_bf16) {
        float*          dinv = (float*)d_ws;
        unsigned short* bufA = (unsigned short*)((char*)d_ws + dinv_b);       // xw (bf16)
        float*          bufB = (float*)((char*)d_ws + dinv_b + nodeH_b);      // agg (f32)

        zero_kernel<<<gN, nThr, 0, stream>>>(dinv, N_NODES);
        deg_kernel<<<gE, nThr, 0, stream>>>(dst, dinv, N_EDGES);
        dinv_kernel<<<gN, nThr, 0, stream>>>(dinv, N_NODES);

        gemm_kernel<F_IN, false, true><<<gN, nThr, 0, stream>>>(x, W1, bufA, N_NODES);
        init_agg_kernel<true><<<gNH4, nThr, 0, stream>>>(bufA, dinv, b1, bufB, N_NODES);
        scatter_kernel<true><<<gEH4, nThr, 0, stream>>>(src, dst, bufA, dinv, bufB, N_EDGES);

        gemm_kernel<HID, true, true><<<gN, nThr, 0, stream>>>(bufB, W2, bufA, N_NODES);
        init_agg_kernel<true><<<gNH4, nThr, 0, stream>>>(bufA, dinv, b2, bufB, N_NODES);
        scatter_kernel<true><<<gEH4, nThr, 0, stream>>>(src, dst, bufA, dinv, bufB, N_EDGES);

        gemm_kernel<HID, true, true><<<gN, nThr, 0, stream>>>(bufB, W3, bufA, N_NODES);
        init_agg_kernel<true><<<gNH4, nThr, 0, stream>>>(bufA, dinv, b3, bufB, N_NODES);
        scatter_kernel<true><<<gEH4, nThr, 0, stream>>>(src, dst, bufA, dinv, bufB, N_EDGES);

        classifier_kernel<<<gN, nThr, 0, stream>>>(bufB, Wc, bc, out, N_NODES);
    } else {
        // workspace too small for any path: deterministic zeros as a diagnostic
        zero_kernel<<<gOut, nThr, 0, stream>>>(out, out_size);
    }
}

// Round 3
// 916.108 us; speedup vs baseline: 9.2760x; 9.2760x over previous
//
#include <hip/hip_runtime.h>
#include <hip/hip_bf16.h>
#include <cstdint>
#include <cstddef>

#define N_NODES 100000
#define N_EDGES 1600000
#define F_IN    256
#define HID     128
#define SCAN_BLK 1024
#define N_SCAN_BLOCKS ((N_NODES + SCAN_BLK - 1) / SCAN_BLK)   // 98

static __device__ inline float bf2f(unsigned short u) {
    return __uint_as_float(((unsigned int)u) << 16);
}
static __device__ inline unsigned short f2bf(float f) {
    union { __hip_bfloat16 h; unsigned short u; } c;
    c.h = __float2bfloat16(f);
    return c.u;
}

// ---------------- utility ----------------

__global__ __launch_bounds__(256) void zero_int_kernel(int* __restrict__ p, int n) {
    int i = blockIdx.x * 256 + threadIdx.x;
    if (i < n) p[i] = 0;
}
__global__ __launch_bounds__(256) void zero_f_kernel(float* __restrict__ p, int n) {
    int i = blockIdx.x * 256 + threadIdx.x;
    if (i < n) p[i] = 0.f;
}

// ---------------- degree histogram + dinv ----------------

__global__ __launch_bounds__(256) void hist_kernel(const int* __restrict__ dst,
                                                   int* __restrict__ deg, int nE) {
    int e = blockIdx.x * 256 + threadIdx.x;
    if (e < nE) atomicAdd(&deg[dst[e]], 1);
}

__global__ __launch_bounds__(256) void dinv_kernel(const int* __restrict__ deg,
                                                   float* __restrict__ dinv, int n) {
    int i = blockIdx.x * 256 + threadIdx.x;
    if (i < n) dinv[i] = rsqrtf((float)deg[i] + 1.0f);   // +1 self-loop
}

// ---------------- exclusive scan (2-level) over deg -> row_ptr ----------------

__global__ __launch_bounds__(256) void scan_reduce_kernel(const int* __restrict__ deg,
                                                          int n, int* __restrict__ blockSums) {
    __shared__ int red[256];
    int base = blockIdx.x * SCAN_BLK;
    int t = threadIdx.x;
    int s = 0;
#pragma unroll
    for (int k = 0; k < 4; ++k) {
        int idx = base + t * 4 + k;
        if (idx < n) s += deg[idx];
    }
    red[t] = s;
    __syncthreads();
    for (int off = 128; off > 0; off >>= 1) {
        if (t < off) red[t] += red[t + off];
        __syncthreads();
    }
    if (t == 0) blockSums[blockIdx.x] = red[0];
}

__global__ __launch_bounds__(64) void scan_sums_kernel(int* __restrict__ blockSums, int nb) {
    if (threadIdx.x == 0 && blockIdx.x == 0) {
        int running = 0;
        for (int i = 0; i < nb; ++i) {
            int v = blockSums[i];
            blockSums[i] = running;
            running += v;
        }
    }
}

__global__ __launch_bounds__(256) void scan_final_kernel(const int* __restrict__ deg, int n,
                                                         const int* __restrict__ blockSums,
                                                         int* __restrict__ row_ptr, int eTotal) {
    __shared__ int pre[256];
    int base = blockIdx.x * SCAN_BLK;
    int t = threadIdx.x;
    int v[4];
    int s = 0;
#pragma unroll
    for (int k = 0; k < 4; ++k) {
        int idx = base + t * 4 + k;
        v[k] = (idx < n) ? deg[idx] : 0;
        s += v[k];
    }
    pre[t] = s;
    __syncthreads();
    // inclusive Hillis-Steele scan over 256 thread sums
    for (int off = 1; off < 256; off <<= 1) {
        int add = (t >= off) ? pre[t - off] : 0;
        __syncthreads();
        pre[t] += add;
        __syncthreads();
    }
    int running = blockSums[blockIdx.x] + pre[t] - s;   // exclusive prefix for this thread
#pragma unroll
    for (int k = 0; k < 4; ++k) {
        int idx = base + t * 4 + k;
        if (idx < n) row_ptr[idx] = running;
        running += v[k];
    }
    if (blockIdx.x == 0 && t == 0) row_ptr[n] = eTotal;
}

// ---------------- CSR fill ----------------

__global__ __launch_bounds__(256) void csr_fill_kernel(const int* __restrict__ src,
                                                       const int* __restrict__ dst,
                                                       const int* __restrict__ row_ptr,
                                                       int* __restrict__ fill,
                                                       int* __restrict__ csr_src, int nE) {
    int e = blockIdx.x * 256 + threadIdx.x;
    if (e >= nE) return;
    int d = dst[e];
    int k = atomicAdd(&fill[d], 1);
    csr_src[row_ptr[d] + k] = src[e];
}

// ---------------- GEMM: Y_bf16[N,128] = X[N,K] @ W[K,128] ----------------

template <int K, bool IN_BF16>
__global__ __launch_bounds__(256) void gemm_kernel(const void* __restrict__ Xv,
                                                   const float* __restrict__ W,
                                                   unsigned short* __restrict__ Y, int n) {
    __shared__ float4 Wl[4096];            // 128 k-rows x 128 cols f32 = 64 KB
    const int row = blockIdx.x * 256 + threadIdx.x;

    float acc[HID];
#pragma unroll
    for (int j = 0; j < HID; ++j) acc[j] = 0.f;

    for (int kc = 0; kc < K; kc += 128) {
        __syncthreads();
        const float4* Wg = reinterpret_cast<const float4*>(W + (size_t)kc * HID);
        for (int t = threadIdx.x; t < 4096; t += 256) Wl[t] = Wg[t];
        __syncthreads();

        if (row < n) {
            auto fma_step = [&](float xv, int k) {
                const float4* wrow = &Wl[k * 32];
#pragma unroll
                for (int j4 = 0; j4 < 32; ++j4) {
                    float4 w = wrow[j4];
                    acc[j4 * 4 + 0] += xv * w.x;
                    acc[j4 * 4 + 1] += xv * w.y;
                    acc[j4 * 4 + 2] += xv * w.z;
                    acc[j4 * 4 + 3] += xv * w.w;
                }
            };
#pragma unroll 2
            for (int k4 = 0; k4 < 32; ++k4) {
                float q0, q1, q2, q3;
                if (IN_BF16) {
                    const unsigned short* xr = (const unsigned short*)Xv + (size_t)row * K + kc;
                    ushort4 q = reinterpret_cast<const ushort4*>(xr)[k4];
                    q0 = bf2f(q.x); q1 = bf2f(q.y); q2 = bf2f(q.z); q3 = bf2f(q.w);
                } else {
                    const float* xr = (const float*)Xv + (size_t)row * K + kc;
                    float4 q = reinterpret_cast<const float4*>(xr)[k4];
                    q0 = q.x; q1 = q.y; q2 = q.z; q3 = q.w;
                }
                fma_step(q0, k4 * 4 + 0);
                fma_step(q1, k4 * 4 + 1);
                fma_step(q2, k4 * 4 + 2);
                fma_step(q3, k4 * 4 + 3);
            }
        }
    }

    if (row < n) {
        ushort4* yr = reinterpret_cast<ushort4*>(Y + (size_t)row * HID);
#pragma unroll
        for (int j4 = 0; j4 < 32; ++j4) {
            ushort4 o;
            o.x = f2bf(acc[j4 * 4 + 0]);
            o.y = f2bf(acc[j4 * 4 + 1]);
            o.z = f2bf(acc[j4 * 4 + 2]);
            o.w = f2bf(acc[j4 * 4 + 3]);
            yr[j4] = o;
        }
    }
}

// ---------------- aggregation (gather, one wave per node) ----------------
// h[v] = relu( dinv[v] * sum_s dinv[s]*xw[s] + dinv[v]^2 * xw[v] + b )

__global__ __launch_bounds__(256) void agg_gather_kernel(const unsigned short* __restrict__ xw,
                                                         const float* __restrict__ dinv,
                                                         const int* __restrict__ row_ptr,
                                                         const int* __restrict__ csr_src,
                                                         const float* __restrict__ b,
                                                         unsigned short* __restrict__ h, int n) {
    int gtid = blockIdx.x * 256 + threadIdx.x;
    int v = gtid >> 6;          // one wave (64 lanes) per node
    if (v >= n) return;
    int lane = threadIdx.x & 63;

    int beg = row_ptr[v];
    int end = row_ptr[v + 1];

    float a0 = 0.f, a1 = 0.f;
    int j = beg;
    for (; j + 1 < end; j += 2) {
        int s0 = csr_src[j];
        int s1 = csr_src[j + 1];
        float d0 = dinv[s0];
        float d1 = dinv[s1];
        ushort2 v0 = *reinterpret_cast<const ushort2*>(xw + (size_t)s0 * HID + 2 * lane);
        ushort2 v1 = *reinterpret_cast<const ushort2*>(xw + (size_t)s1 * HID + 2 * lane);
        a0 += d0 * bf2f(v0.x) + d1 * bf2f(v1.x);
        a1 += d0 * bf2f(v0.y) + d1 * bf2f(v1.y);
    }
    if (j < end) {
        int s0 = csr_src[j];
        float d0 = dinv[s0];
        ushort2 v0 = *reinterpret_cast<const ushort2*>(xw + (size_t)s0 * HID + 2 * lane);
        a0 += d0 * bf2f(v0.x);
        a1 += d0 * bf2f(v0.y);
    }

    float dv = dinv[v];
    ushort2 vs = *reinterpret_cast<const ushort2*>(xw + (size_t)v * HID + 2 * lane);
    float2 bb = *reinterpret_cast<const float2*>(b + 2 * lane);
    float r0 = dv * a0 + dv * dv * bf2f(vs.x) + bb.x;
    float r1 = dv * a1 + dv * dv * bf2f(vs.y) + bb.y;
    r0 = fmaxf(r0, 0.f);
    r1 = fmaxf(r1, 0.f);
    ushort2 o;
    o.x = f2bf(r0);
    o.y = f2bf(r1);
    *reinterpret_cast<ushort2*>(h + (size_t)v * HID + 2 * lane) = o;
}

// ---------------- classifier + log_softmax (h is post-relu bf16) ----------------

__global__ __launch_bounds__(256) void classifier_kernel(const unsigned short* __restrict__ h,
                                                         const float* __restrict__ Wc,
                                                         const float* __restrict__ bc,
                                                         float* __restrict__ out, int n) {
    __shared__ float wc0[HID], wc1[HID], bcs[2];
    if (threadIdx.x < HID) {
        wc0[threadIdx.x] = Wc[threadIdx.x * 2 + 0];
        wc1[threadIdx.x] = Wc[threadIdx.x * 2 + 1];
    }
    if (threadIdx.x < 2) bcs[threadIdx.x] = bc[threadIdx.x];
    __syncthreads();

    int i = blockIdx.x * 256 + threadIdx.x;
    if (i >= n) return;
    const ushort4* hr = reinterpret_cast<const ushort4*>(h + (size_t)i * HID);
    float l0 = 0.f, l1 = 0.f;
#pragma unroll
    for (int j4 = 0; j4 < 32; ++j4) {
        ushort4 q = hr[j4];
        float v0 = bf2f(q.x), v1 = bf2f(q.y), v2 = bf2f(q.z), v3 = bf2f(q.w);
        l0 += v0 * wc0[j4 * 4 + 0] + v1 * wc0[j4 * 4 + 1]
            + v2 * wc0[j4 * 4 + 2] + v3 * wc0[j4 * 4 + 3];
        l1 += v0 * wc1[j4 * 4 + 0] + v1 * wc1[j4 * 4 + 1]
            + v2 * wc1[j4 * 4 + 2] + v3 * wc1[j4 * 4 + 3];
    }
    l0 += bcs[0]; l1 += bcs[1];
    float m = fmaxf(l0, l1);
    float lse = m + logf(expf(l0 - m) + expf(l1 - m));
    out[i * 2 + 0] = l0 - lse;
    out[i * 2 + 1] = l1 - lse;
}

// ---------------- launch ----------------

static inline size_t align256(size_t x) { return (x + 255) & ~(size_t)255; }

extern "C" void kernel_launch(void* const* d_in, const int* in_sizes, int n_in,
                              void* d_out, int out_size, void* d_ws, size_t ws_size,
                              hipStream_t stream) {
    const float* x   = (const float*)d_in[0];
    const int*   ei  = (const int*)d_in[1];     // int32 per harness contract
    const float* W1  = (const float*)d_in[2];
    const float* b1  = (const float*)d_in[3];
    const float* W2  = (const float*)d_in[4];
    const float* b2  = (const float*)d_in[5];
    const float* W3  = (const float*)d_in[6];
    const float* b3  = (const float*)d_in[7];
    const float* Wc  = (const float*)d_in[8];
    const float* bc  = (const float*)d_in[9];
    float*       out = (float*)d_out;

    const int* src = ei;             // edge_index[0,:]
    const int* dst = ei + N_EDGES;   // edge_index[1,:]

    // workspace layout (all aligned to 256B)
    size_t off = 0;
    size_t o_dinv    = off; off = align256(off + (size_t)N_NODES * 4);
    size_t o_deg     = off; off = align256(off + (size_t)N_NODES * 4);
    size_t o_rowptr  = off; off = align256(off + (size_t)(N_NODES + 1) * 4);
    size_t o_fill    = off; off = align256(off + (size_t)N_NODES * 4);
    size_t o_bsums   = off; off = align256(off + (size_t)N_SCAN_BLOCKS * 4);
    size_t o_csr     = off; off = align256(off + (size_t)N_EDGES * 4);
    size_t o_bufA    = off; off = align256(off + (size_t)N_NODES * HID * 2);
    size_t o_bufB    = off; off = align256(off + (size_t)N_NODES * HID * 2);
    size_t need = off;                           // ~59.3 MB

    const int nThr = 256;
    const int gOut = (out_size + nThr - 1) / nThr;
    if (ws_size < need) {   // diagnostic fallback: zeros
        zero_f_kernel<<<gOut, nThr, 0, stream>>>(out, out_size);
        return;
    }

    char* ws = (char*)d_ws;
    float*          dinv    = (float*)(ws + o_dinv);
    int*            deg     = (int*)(ws + o_deg);
    int*            row_ptr = (int*)(ws + o_rowptr);
    int*            fill    = (int*)(ws + o_fill);
    int*            bsums   = (int*)(ws + o_bsums);
    int*            csr_src = (int*)(ws + o_csr);
    unsigned short* bufA    = (unsigned short*)(ws + o_bufA);   // xw (bf16)
    unsigned short* bufB    = (unsigned short*)(ws + o_bufB);   // h  (bf16)

    const int gN  = (N_NODES + nThr - 1) / nThr;
    const int gE  = (N_EDGES + nThr - 1) / nThr;
    const int gW  = (N_NODES * 64 + nThr - 1) / nThr;   // wave-per-node grids (25.6M threads)

    // CSR build
    zero_int_kernel<<<gN, nThr, 0, stream>>>(deg, N_NODES);
    zero_int_kernel<<<gN, nThr, 0, stream>>>(fill, N_NODES);
    hist_kernel<<<gE, nThr, 0, stream>>>(dst, deg, N_EDGES);
    dinv_kernel<<<gN, nThr, 0, stream>>>(deg, dinv, N_NODES);
    scan_reduce_kernel<<<N_SCAN_BLOCKS, nThr, 0, stream>>>(deg, N_NODES, bsums);
    scan_sums_kernel<<<1, 64, 0, stream>>>(bsums, N_SCAN_BLOCKS);
    scan_final_kernel<<<N_SCAN_BLOCKS, nThr, 0, stream>>>(deg, N_NODES, bsums, row_ptr, N_EDGES);
    csr_fill_kernel<<<gE, nThr, 0, stream>>>(src, dst, row_ptr, fill, csr_src, N_EDGES);

    // layer 1
    gemm_kernel<F_IN, false><<<gN, nThr, 0, stream>>>(x, W1, bufA, N_NODES);
    agg_gather_kernel<<<gW, nThr, 0, stream>>>(bufA, dinv, row_ptr, csr_src, b1, bufB, N_NODES);
    // layer 2
    gemm_kernel<HID, true><<<gN, nThr, 0, stream>>>(bufB, W2, bufA, N_NODES);
    agg_gather_kernel<<<gW, nThr, 0, stream>>>(bufA, dinv, row_ptr, csr_src, b2, bufB, N_NODES);
    // layer 3
    gemm_kernel<HID, true><<<gN, nThr, 0, stream>>>(bufB, W3, bufA, N_NODES);
    agg_gather_kernel<<<gW, nThr, 0, stream>>>(bufA, dinv, row_ptr, csr_src, b3, bufB, N_NODES);

    // classifier
    classifier_kernel<<<gN, nThr, 0, stream>>>(bufB, Wc, bc, out, N_NODES);
}

// Round 4
// 589.061 us; speedup vs baseline: 14.4260x; 1.5552x over previous
//
#include <hip/hip_runtime.h>
#include <hip/hip_bf16.h>
#include <cstdint>
#include <cstddef>

#define N_NODES 100000
#define N_EDGES 1600000
#define F_IN    256
#define HID     128
#define SCAN_BLK 1024
#define N_SCAN_BLOCKS ((N_NODES + SCAN_BLK - 1) / SCAN_BLK)   // 98

typedef __attribute__((ext_vector_type(8))) short  bf16x8;
typedef __attribute__((ext_vector_type(4))) float  f32x4;

static __device__ inline float bf2f(unsigned short u) {
    return __uint_as_float(((unsigned int)u) << 16);
}
static __device__ inline unsigned short f2bf(float f) {
    union { __hip_bfloat16 h; unsigned short u; } c;
    c.h = __float2bfloat16(f);
    return c.u;
}

// ---------------- utility ----------------

__global__ __launch_bounds__(256) void zero_int_kernel(int* __restrict__ p, int n) {
    int i = blockIdx.x * 256 + threadIdx.x;
    if (i < n) p[i] = 0;
}
__global__ __launch_bounds__(256) void zero_f_kernel(float* __restrict__ p, int n) {
    int i = blockIdx.x * 256 + threadIdx.x;
    if (i < n) p[i] = 0.f;
}

// ---------------- degree histogram + dinv ----------------

__global__ __launch_bounds__(256) void hist_kernel(const int* __restrict__ dst,
                                                   int* __restrict__ deg, int nE) {
    int e = blockIdx.x * 256 + threadIdx.x;
    if (e < nE) atomicAdd(&deg[dst[e]], 1);
}

__global__ __launch_bounds__(256) void dinv_kernel(const int* __restrict__ deg,
                                                   float* __restrict__ dinv, int n) {
    int i = blockIdx.x * 256 + threadIdx.x;
    if (i < n) dinv[i] = rsqrtf((float)deg[i] + 1.0f);   // +1 self-loop
}

// ---------------- exclusive scan (2-level) over deg -> row_ptr ----------------

__global__ __launch_bounds__(256) void scan_reduce_kernel(const int* __restrict__ deg,
                                                          int n, int* __restrict__ blockSums) {
    __shared__ int red[256];
    int base = blockIdx.x * SCAN_BLK;
    int t = threadIdx.x;
    int s = 0;
#pragma unroll
    for (int k = 0; k < 4; ++k) {
        int idx = base + t * 4 + k;
        if (idx < n) s += deg[idx];
    }
    red[t] = s;
    __syncthreads();
    for (int off = 128; off > 0; off >>= 1) {
        if (t < off) red[t] += red[t + off];
        __syncthreads();
    }
    if (t == 0) blockSums[blockIdx.x] = red[0];
}

__global__ __launch_bounds__(64) void scan_sums_kernel(int* __restrict__ blockSums, int nb) {
    if (threadIdx.x == 0 && blockIdx.x == 0) {
        int running = 0;
        for (int i = 0; i < nb; ++i) {
            int v = blockSums[i];
            blockSums[i] = running;
            running += v;
        }
    }
}

__global__ __launch_bounds__(256) void scan_final_kernel(const int* __restrict__ deg, int n,
                                                         const int* __restrict__ blockSums,
                                                         int* __restrict__ row_ptr, int eTotal) {
    __shared__ int pre[256];
    int base = blockIdx.x * SCAN_BLK;
    int t = threadIdx.x;
    int v[4];
    int s = 0;
#pragma unroll
    for (int k = 0; k < 4; ++k) {
        int idx = base + t * 4 + k;
        v[k] = (idx < n) ? deg[idx] : 0;
        s += v[k];
    }
    pre[t] = s;
    __syncthreads();
    for (int off = 1; off < 256; off <<= 1) {
        int add = (t >= off) ? pre[t - off] : 0;
        __syncthreads();
        pre[t] += add;
        __syncthreads();
    }
    int running = blockSums[blockIdx.x] + pre[t] - s;
#pragma unroll
    for (int k = 0; k < 4; ++k) {
        int idx = base + t * 4 + k;
        if (idx < n) row_ptr[idx] = running;
        running += v[k];
    }
    if (blockIdx.x == 0 && t == 0) row_ptr[n] = eTotal;
}

// ---------------- CSR fill ----------------

__global__ __launch_bounds__(256) void csr_fill_kernel(const int* __restrict__ src,
                                                       const int* __restrict__ dst,
                                                       const int* __restrict__ row_ptr,
                                                       int* __restrict__ fill,
                                                       int* __restrict__ csr_src, int nE) {
    int e = blockIdx.x * 256 + threadIdx.x;
    if (e >= nE) return;
    int d = dst[e];
    int k = atomicAdd(&fill[d], 1);
    csr_src[row_ptr[d] + k] = src[e];
}

// ---------------- W -> fragment blob (bf16, MFMA B-operand order) -----------
// blob entry tid = (s*8 + c)*64 + lane, holding 8 bf16:
//   W[k = s*32 + (lane>>4)*8 + j][col = c*16 + (lane&15)],  j = 0..7

template <int K>
__global__ __launch_bounds__(256) void prep_blob_kernel(const float* __restrict__ W,
                                                        unsigned short* __restrict__ blob) {
    constexpr int TOT = (K / 32) * 8 * 64;
    int tid = blockIdx.x * 256 + threadIdx.x;
    if (tid >= TOT) return;
    int lane = tid & 63;
    int c    = (tid >> 6) & 7;
    int s    = tid >> 9;
    int col  = c * 16 + (lane & 15);
    int kb   = s * 32 + (lane >> 4) * 8;
    bf16x8 o;
#pragma unroll
    for (int j = 0; j < 8; ++j)
        o[j] = (short)f2bf(W[(size_t)(kb + j) * HID + col]);
    *reinterpret_cast<bf16x8*>(blob + (size_t)tid * 8) = o;
}

// ---------------- MFMA GEMM: Y_bf16[N,128] = X[N,K] @ W[K,128] --------------
// 4 waves/block, 32 rows/wave (2 row-frags), 8 col-frags, no LDS.

template <int K, bool IN_BF16>
__global__ __launch_bounds__(256) void mfma_gemm_kernel(const void* __restrict__ Xv,
                                                        const unsigned short* __restrict__ blob,
                                                        unsigned short* __restrict__ Y, int n) {
    constexpr int KSTEPS = K / 32;
    const int lane = threadIdx.x & 63;
    const int wave = threadIdx.x >> 6;
    const int rowbase = blockIdx.x * 128 + wave * 32;

    const int r0 = min(rowbase +      (lane & 15), n - 1);
    const int r1 = min(rowbase + 16 + (lane & 15), n - 1);
    const int koff = (lane >> 4) * 8;

    f32x4 acc0[8], acc1[8];
#pragma unroll
    for (int c = 0; c < 8; ++c) { acc0[c] = (f32x4)0.f; acc1[c] = (f32x4)0.f; }

#pragma unroll
    for (int s = 0; s < KSTEPS; ++s) {
        // B fragments (L2-resident broadcast)
        bf16x8 bfr[8];
#pragma unroll
        for (int c = 0; c < 8; ++c)
            bfr[c] = *reinterpret_cast<const bf16x8*>(blob + ((size_t)((s * 8 + c) * 64 + lane)) * 8);

        // A fragments
        bf16x8 a0, a1;
        if (IN_BF16) {
            const unsigned short* Xb = (const unsigned short*)Xv;
            a0 = *reinterpret_cast<const bf16x8*>(Xb + (size_t)r0 * K + s * 32 + koff);
            a1 = *reinterpret_cast<const bf16x8*>(Xb + (size_t)r1 * K + s * 32 + koff);
        } else {
            const float* Xf = (const float*)Xv;
            const float4* p0 = reinterpret_cast<const float4*>(Xf + (size_t)r0 * K + s * 32 + koff);
            const float4* p1 = reinterpret_cast<const float4*>(Xf + (size_t)r1 * K + s * 32 + koff);
            float4 q0 = p0[0], q1 = p0[1], q2 = p1[0], q3 = p1[1];
            a0[0] = (short)f2bf(q0.x); a0[1] = (short)f2bf(q0.y);
            a0[2] = (short)f2bf(q0.z); a0[3] = (short)f2bf(q0.w);
            a0[4] = (short)f2bf(q1.x); a0[5] = (short)f2bf(q1.y);
            a0[6] = (short)f2bf(q1.z); a0[7] = (short)f2bf(q1.w);
            a1[0] = (short)f2bf(q2.x); a1[1] = (short)f2bf(q2.y);
            a1[2] = (short)f2bf(q2.z); a1[3] = (short)f2bf(q2.w);
            a1[4] = (short)f2bf(q3.x); a1[5] = (short)f2bf(q3.y);
            a1[6] = (short)f2bf(q3.z); a1[7] = (short)f2bf(q3.w);
        }

#pragma unroll
        for (int c = 0; c < 8; ++c) {
            acc0[c] = __builtin_amdgcn_mfma_f32_16x16x32_bf16(a0, bfr[c], acc0[c], 0, 0, 0);
            acc1[c] = __builtin_amdgcn_mfma_f32_16x16x32_bf16(a1, bfr[c], acc1[c], 0, 0, 0);
        }
    }

    // epilogue: D[row=(lane>>4)*4+r][col=lane&15] per 16x16 frag
    const int col  = lane & 15;
    const int rsub = (lane >> 4) * 4;
#pragma unroll
    for (int c = 0; c < 8; ++c) {
#pragma unroll
        for (int r = 0; r < 4; ++r) {
            int row0 = rowbase + rsub + r;
            int row1 = rowbase + 16 + rsub + r;
            if (row0 < n) Y[(size_t)row0 * HID + c * 16 + col] = f2bf(acc0[c][r]);
            if (row1 < n) Y[(size_t)row1 * HID + c * 16 + col] = f2bf(acc1[c][r]);
        }
    }
}

// ---------------- aggregation (gather, one wave per node) ----------------
// h[v] = relu( dinv[v] * sum_s dinv[s]*xw[s] + dinv[v]^2 * xw[v] + b )

__global__ __launch_bounds__(256) void agg_gather_kernel(const unsigned short* __restrict__ xw,
                                                         const float* __restrict__ dinv,
                                                         const int* __restrict__ row_ptr,
                                                         const int* __restrict__ csr_src,
                                                         const float* __restrict__ b,
                                                         unsigned short* __restrict__ h, int n) {
    int gtid = blockIdx.x * 256 + threadIdx.x;
    int v = gtid >> 6;          // one wave per node
    if (v >= n) return;
    int lane = threadIdx.x & 63;

    int beg = row_ptr[v];
    int end = row_ptr[v + 1];

    float a0 = 0.f, a1 = 0.f;
    int j = beg;
    for (; j + 1 < end; j += 2) {
        int s0 = csr_src[j];
        int s1 = csr_src[j + 1];
        float d0 = dinv[s0];
        float d1 = dinv[s1];
        ushort2 v0 = *reinterpret_cast<const ushort2*>(xw + (size_t)s0 * HID + 2 * lane);
        ushort2 v1 = *reinterpret_cast<const ushort2*>(xw + (size_t)s1 * HID + 2 * lane);
        a0 += d0 * bf2f(v0.x) + d1 * bf2f(v1.x);
        a1 += d0 * bf2f(v0.y) + d1 * bf2f(v1.y);
    }
    if (j < end) {
        int s0 = csr_src[j];
        float d0 = dinv[s0];
        ushort2 v0 = *reinterpret_cast<const ushort2*>(xw + (size_t)s0 * HID + 2 * lane);
        a0 += d0 * bf2f(v0.x);
        a1 += d0 * bf2f(v0.y);
    }

    float dv = dinv[v];
    ushort2 vs = *reinterpret_cast<const ushort2*>(xw + (size_t)v * HID + 2 * lane);
    float2 bb = *reinterpret_cast<const float2*>(b + 2 * lane);
    float r0 = fmaxf(dv * a0 + dv * dv * bf2f(vs.x) + bb.x, 0.f);
    float r1 = fmaxf(dv * a1 + dv * dv * bf2f(vs.y) + bb.y, 0.f);
    ushort2 o;
    o.x = f2bf(r0);
    o.y = f2bf(r1);
    *reinterpret_cast<ushort2*>(h + (size_t)v * HID + 2 * lane) = o;
}

// ---------------- classifier + log_softmax ----------------

__global__ __launch_bounds__(256) void classifier_kernel(const unsigned short* __restrict__ h,
                                                         const float* __restrict__ Wc,
                                                         const float* __restrict__ bc,
                                                         float* __restrict__ out, int n) {
    __shared__ float wc0[HID], wc1[HID], bcs[2];
    if (threadIdx.x < HID) {
        wc0[threadIdx.x] = Wc[threadIdx.x * 2 + 0];
        wc1[threadIdx.x] = Wc[threadIdx.x * 2 + 1];
    }
    if (threadIdx.x < 2) bcs[threadIdx.x] = bc[threadIdx.x];
    __syncthreads();

    int i = blockIdx.x * 256 + threadIdx.x;
    if (i >= n) return;
    const ushort4* hr = reinterpret_cast<const ushort4*>(h + (size_t)i * HID);
    float l0 = 0.f, l1 = 0.f;
#pragma unroll
    for (int j4 = 0; j4 < 32; ++j4) {
        ushort4 q = hr[j4];
        float v0 = bf2f(q.x), v1 = bf2f(q.y), v2 = bf2f(q.z), v3 = bf2f(q.w);
        l0 += v0 * wc0[j4 * 4 + 0] + v1 * wc0[j4 * 4 + 1]
            + v2 * wc0[j4 * 4 + 2] + v3 * wc0[j4 * 4 + 3];
        l1 += v0 * wc1[j4 * 4 + 0] + v1 * wc1[j4 * 4 + 1]
            + v2 * wc1[j4 * 4 + 2] + v3 * wc1[j4 * 4 + 3];
    }
    l0 += bcs[0]; l1 += bcs[1];
    float m = fmaxf(l0, l1);
    float lse = m + logf(expf(l0 - m) + expf(l1 - m));
    out[i * 2 + 0] = l0 - lse;
    out[i * 2 + 1] = l1 - lse;
}

// ---------------- launch ----------------

static inline size_t align256(size_t x) { return (x + 255) & ~(size_t)255; }

extern "C" void kernel_launch(void* const* d_in, const int* in_sizes, int n_in,
                              void* d_out, int out_size, void* d_ws, size_t ws_size,
                              hipStream_t stream) {
    const float* x   = (const float*)d_in[0];
    const int*   ei  = (const int*)d_in[1];     // int32 per harness contract
    const float* W1  = (const float*)d_in[2];
    const float* b1  = (const float*)d_in[3];
    const float* W2  = (const float*)d_in[4];
    const float* b2  = (const float*)d_in[5];
    const float* W3  = (const float*)d_in[6];
    const float* b3  = (const float*)d_in[7];
    const float* Wc  = (const float*)d_in[8];
    const float* bc  = (const float*)d_in[9];
    float*       out = (float*)d_out;

    const int* src = ei;             // edge_index[0,:]
    const int* dst = ei + N_EDGES;   // edge_index[1,:]

    // workspace layout
    size_t off = 0;
    size_t o_dinv    = off; off = align256(off + (size_t)N_NODES * 4);
    size_t o_deg     = off; off = align256(off + (size_t)N_NODES * 4);
    size_t o_rowptr  = off; off = align256(off + (size_t)(N_NODES + 1) * 4);
    size_t o_fill    = off; off = align256(off + (size_t)N_NODES * 4);
    size_t o_bsums   = off; off = align256(off + (size_t)N_SCAN_BLOCKS * 4);
    size_t o_csr     = off; off = align256(off + (size_t)N_EDGES * 4);
    size_t o_blob1   = off; off = align256(off + (size_t)(F_IN / 32) * 8 * 64 * 8 * 2); // 64KB
    size_t o_blob2   = off; off = align256(off + (size_t)(HID / 32) * 8 * 64 * 8 * 2);  // 32KB
    size_t o_blob3   = off; off = align256(off + (size_t)(HID / 32) * 8 * 64 * 8 * 2);  // 32KB
    size_t o_bufA    = off; off = align256(off + (size_t)N_NODES * HID * 2);
    size_t o_bufB    = off; off = align256(off + (size_t)N_NODES * HID * 2);
    size_t need = off;                           // ~59.5 MB

    const int nThr = 256;
    const int gOut = (out_size + nThr - 1) / nThr;
    if (ws_size < need) {
        zero_f_kernel<<<gOut, nThr, 0, stream>>>(out, out_size);
        return;
    }

    char* ws = (char*)d_ws;
    float*          dinv    = (float*)(ws + o_dinv);
    int*            deg     = (int*)(ws + o_deg);
    int*            row_ptr = (int*)(ws + o_rowptr);
    int*            fill    = (int*)(ws + o_fill);
    int*            bsums   = (int*)(ws + o_bsums);
    int*            csr_src = (int*)(ws + o_csr);
    unsigned short* blob1   = (unsigned short*)(ws + o_blob1);
    unsigned short* blob2   = (unsigned short*)(ws + o_blob2);
    unsigned short* blob3   = (unsigned short*)(ws + o_blob3);
    unsigned short* bufA    = (unsigned short*)(ws + o_bufA);   // xw (bf16)
    unsigned short* bufB    = (unsigned short*)(ws + o_bufB);   // h  (bf16)

    const int gN  = (N_NODES + nThr - 1) / nThr;
    const int gE  = (N_EDGES + nThr - 1) / nThr;
    const int gW  = (N_NODES * 64 + nThr - 1) / nThr;
    const int gG  = (N_NODES + 127) / 128;               // mfma gemm blocks

    // CSR build
    zero_int_kernel<<<gN, nThr, 0, stream>>>(deg, N_NODES);
    zero_int_kernel<<<gN, nThr, 0, stream>>>(fill, N_NODES);
    hist_kernel<<<gE, nThr, 0, stream>>>(dst, deg, N_EDGES);
    dinv_kernel<<<gN, nThr, 0, stream>>>(deg, dinv, N_NODES);
    scan_reduce_kernel<<<N_SCAN_BLOCKS, nThr, 0, stream>>>(deg, N_NODES, bsums);
    scan_sums_kernel<<<1, 64, 0, stream>>>(bsums, N_SCAN_BLOCKS);
    scan_final_kernel<<<N_SCAN_BLOCKS, nThr, 0, stream>>>(deg, N_NODES, bsums, row_ptr, N_EDGES);
    csr_fill_kernel<<<gE, nThr, 0, stream>>>(src, dst, row_ptr, fill, csr_src, N_EDGES);

    // W blobs
    prep_blob_kernel<F_IN><<<16, nThr, 0, stream>>>(W1, blob1);
    prep_blob_kernel<HID><<<8, nThr, 0, stream>>>(W2, blob2);
    prep_blob_kernel<HID><<<8, nThr, 0, stream>>>(W3, blob3);

    // layer 1
    mfma_gemm_kernel<F_IN, false><<<gG, nThr, 0, stream>>>(x, blob1, bufA, N_NODES);
    agg_gather_kernel<<<gW, nThr, 0, stream>>>(bufA, dinv, row_ptr, csr_src, b1, bufB, N_NODES);
    // layer 2
    mfma_gemm_kernel<HID, true><<<gG, nThr, 0, stream>>>(bufB, blob2, bufA, N_NODES);
    agg_gather_kernel<<<gW, nThr, 0, stream>>>(bufA, dinv, row_ptr, csr_src, b2, bufB, N_NODES);
    // layer 3
    mfma_gemm_kernel<HID, true><<<gG, nThr, 0, stream>>>(bufB, W3 ? blob3 : blob3, bufA, N_NODES);
    agg_gather_kernel<<<gW, nThr, 0, stream>>>(bufA, dinv, row_ptr, csr_src, b3, bufB, N_NODES);

    // classifier
    classifier_kernel<<<gN, nThr, 0, stream>>>(bufB, Wc, bc, out, N_NODES);
}

// Round 5
// 361.580 us; speedup vs baseline: 23.5018x; 1.6291x over previous
//
#include <hip/hip_runtime.h>
#include <hip/hip_bf16.h>
#include <cstdint>
#include <cstddef>

#define N_NODES 100000
#define N_EDGES 1600000
#define F_IN    256
#define HID     128
#define SCAN_BLK 1024
#define N_SCAN_BLOCKS ((N_NODES + SCAN_BLK - 1) / SCAN_BLK)   // 98
#define NB       ((N_NODES + 255) >> 8)                        // 391 dst-buckets
#define F3_CHUNK 7168
#define N_CHUNKS ((N_EDGES + F3_CHUNK - 1) / F3_CHUNK)         // 224

typedef __attribute__((ext_vector_type(8))) short  bf16x8;
typedef __attribute__((ext_vector_type(4))) float  f32x4;

static __device__ inline float bf2f(unsigned short u) {
    return __uint_as_float(((unsigned int)u) << 16);
}
static __device__ inline unsigned short f2bf(float f) {
    union { __hip_bfloat16 h; unsigned short u; } c;
    c.h = __float2bfloat16(f);
    return c.u;
}
static __device__ inline float lof(unsigned int w) { return __uint_as_float(w << 16); }
static __device__ inline float hif(unsigned int w) { return __uint_as_float(w & 0xffff0000u); }

// ---------------- utility ----------------

__global__ __launch_bounds__(256) void zero_int_kernel(int* __restrict__ p, int n) {
    int i = blockIdx.x * 256 + threadIdx.x;
    if (i < n) p[i] = 0;
}
__global__ __launch_bounds__(256) void zero_f_kernel(float* __restrict__ p, int n) {
    int i = blockIdx.x * 256 + threadIdx.x;
    if (i < n) p[i] = 0.f;
}

// ---------------- bucketed CSR build ----------------
// F1: per-chunk LDS bucket histogram -> global bcnt

__global__ __launch_bounds__(256) void bucket_count_kernel(const int* __restrict__ dst,
                                                           int* __restrict__ bcnt, int nE) {
    __shared__ int c[NB];
    for (int i = threadIdx.x; i < NB; i += 256) c[i] = 0;
    __syncthreads();
    int base = blockIdx.x * F3_CHUNK;
    int m = min(F3_CHUNK, nE - base);
    for (int t = threadIdx.x; t < m; t += 256)
        atomicAdd(&c[dst[base + t] >> 8], 1);
    __syncthreads();
    for (int i = threadIdx.x; i < NB; i += 256)
        if (c[i]) atomicAdd(&bcnt[i], c[i]);
}

// F2: exclusive scan of 391 bucket counts (single block)

__global__ __launch_bounds__(512) void scan_bucket_kernel(const int* __restrict__ bcnt,
                                                          int* __restrict__ bbase) {
    __shared__ int s[512];
    int t = threadIdx.x;
    int v = (t < NB) ? bcnt[t] : 0;
    s[t] = v;
    __syncthreads();
    for (int off = 1; off < 512; off <<= 1) {
        int add = (t >= off) ? s[t - off] : 0;
        __syncthreads();
        s[t] += add;
        __syncthreads();
    }
    if (t < NB) bbase[t] = s[t] - v;
    if (t == 0) bbase[NB] = N_EDGES;
}

// F3: stage edges grouped by bucket (LDS stash, contiguous writes per bucket run)

__global__ __launch_bounds__(256) void stage_kernel(const int* __restrict__ src,
                                                    const int* __restrict__ dst,
                                                    const int* __restrict__ bbase,
                                                    int* __restrict__ gfill,
                                                    int* __restrict__ stg_src,
                                                    int* __restrict__ stg_dst, int nE) {
    __shared__ int ss[F3_CHUNK];
    __shared__ int sd[F3_CHUNK];
    __shared__ int cnt[NB];
    __shared__ int bas[NB];
    int base = blockIdx.x * F3_CHUNK;
    int m = min(F3_CHUNK, nE - base);
    for (int i = threadIdx.x; i < NB; i += 256) cnt[i] = 0;
    __syncthreads();
    for (int t = threadIdx.x; t < m; t += 256) {
        int s = src[base + t];
        int d = dst[base + t];
        ss[t] = s;
        sd[t] = d;
        atomicAdd(&cnt[d >> 8], 1);
    }
    __syncthreads();
    for (int i = threadIdx.x; i < NB; i += 256) {
        int c = cnt[i];
        bas[i] = bbase[i] + (c ? atomicAdd(&gfill[i], c) : 0);
        cnt[i] = 0;
    }
    __syncthreads();
    for (int t = threadIdx.x; t < m; t += 256) {
        int d = sd[t];
        int bkt = d >> 8;
        int k = atomicAdd(&cnt[bkt], 1);
        int pos = bas[bkt] + k;
        stg_src[pos] = ss[t];
        stg_dst[pos] = d;
    }
}

// H2: per-bucket degree count in LDS (dense deg write, replaces random-atomic hist)

__global__ __launch_bounds__(256) void bucket_deg_kernel(const int* __restrict__ stg_dst,
                                                         const int* __restrict__ bbase,
                                                         int* __restrict__ deg, int n) {
    __shared__ int c[256];
    c[threadIdx.x] = 0;
    __syncthreads();
    int b = blockIdx.x;
    int beg = bbase[b], end = bbase[b + 1];
    for (int t = beg + threadIdx.x; t < end; t += 256)
        atomicAdd(&c[stg_dst[t] & 255], 1);
    __syncthreads();
    int node = b * 256 + threadIdx.x;
    if (node < n) deg[node] = c[threadIdx.x];
}

// F4: per-bucket CSR fill — all csr writes confined to ~16KB window (one CU's L2)

__global__ __launch_bounds__(256) void bucket_fill_kernel(const int* __restrict__ stg_src,
                                                          const int* __restrict__ stg_dst,
                                                          const int* __restrict__ bbase,
                                                          const int* __restrict__ row_ptr,
                                                          int* __restrict__ csr_src) {
    __shared__ int c[256];
    c[threadIdx.x] = 0;
    __syncthreads();
    int b = blockIdx.x;
    int beg = bbase[b], end = bbase[b + 1];
    for (int t = beg + threadIdx.x; t < end; t += 256) {
        int d = stg_dst[t];
        int k = atomicAdd(&c[d & 255], 1);
        csr_src[row_ptr[d] + k] = stg_src[t];
    }
}

// ---------------- dinv ----------------

__global__ __launch_bounds__(256) void dinv_kernel(const int* __restrict__ deg,
                                                   float* __restrict__ dinv, int n) {
    int i = blockIdx.x * 256 + threadIdx.x;
    if (i < n) dinv[i] = rsqrtf((float)deg[i] + 1.0f);   // +1 self-loop
}

// ---------------- exclusive scan (2-level) over deg -> row_ptr ----------------

__global__ __launch_bounds__(256) void scan_reduce_kernel(const int* __restrict__ deg,
                                                          int n, int* __restrict__ blockSums) {
    __shared__ int red[256];
    int base = blockIdx.x * SCAN_BLK;
    int t = threadIdx.x;
    int s = 0;
#pragma unroll
    for (int k = 0; k < 4; ++k) {
        int idx = base + t * 4 + k;
        if (idx < n) s += deg[idx];
    }
    red[t] = s;
    __syncthreads();
    for (int off = 128; off > 0; off >>= 1) {
        if (t < off) red[t] += red[t + off];
        __syncthreads();
    }
    if (t == 0) blockSums[blockIdx.x] = red[0];
}

__global__ __launch_bounds__(128) void scan_small_kernel(int* __restrict__ data, int n) {
    __shared__ int s[128];
    int t = threadIdx.x;
    int v = (t < n) ? data[t] : 0;
    s[t] = v;
    __syncthreads();
    for (int off = 1; off < 128; off <<= 1) {
        int add = (t >= off) ? s[t - off] : 0;
        __syncthreads();
        s[t] += add;
        __syncthreads();
    }
    if (t < n) data[t] = s[t] - v;   // exclusive
}

__global__ __launch_bounds__(256) void scan_final_kernel(const int* __restrict__ deg, int n,
                                                         const int* __restrict__ blockSums,
                                                         int* __restrict__ row_ptr, int eTotal) {
    __shared__ int pre[256];
    int base = blockIdx.x * SCAN_BLK;
    int t = threadIdx.x;
    int v[4];
    int s = 0;
#pragma unroll
    for (int k = 0; k < 4; ++k) {
        int idx = base + t * 4 + k;
        v[k] = (idx < n) ? deg[idx] : 0;
        s += v[k];
    }
    pre[t] = s;
    __syncthreads();
    for (int off = 1; off < 256; off <<= 1) {
        int add = (t >= off) ? pre[t - off] : 0;
        __syncthreads();
        pre[t] += add;
        __syncthreads();
    }
    int running = blockSums[blockIdx.x] + pre[t] - s;
#pragma unroll
    for (int k = 0; k < 4; ++k) {
        int idx = base + t * 4 + k;
        if (idx < n) row_ptr[idx] = running;
        running += v[k];
    }
    if (blockIdx.x == 0 && t == 0) row_ptr[n] = eTotal;
}

// ---------------- W -> fragment blob (bf16, MFMA B-operand order) -----------

template <int K>
__global__ __launch_bounds__(256) void prep_blob_kernel(const float* __restrict__ W,
                                                        unsigned short* __restrict__ blob) {
    constexpr int TOT = (K / 32) * 8 * 64;
    int tid = blockIdx.x * 256 + threadIdx.x;
    if (tid >= TOT) return;
    int lane = tid & 63;
    int c    = (tid >> 6) & 7;
    int s    = tid >> 9;
    int col  = c * 16 + (lane & 15);
    int kb   = s * 32 + (lane >> 4) * 8;
    bf16x8 o;
#pragma unroll
    for (int j = 0; j < 8; ++j)
        o[j] = (short)f2bf(W[(size_t)(kb + j) * HID + col]);
    *reinterpret_cast<bf16x8*>(blob + (size_t)tid * 8) = o;
}

// ---------------- MFMA GEMM: Y_bf16[N,128] = X[N,K] @ W[K,128] --------------

template <int K, bool IN_BF16>
__global__ __launch_bounds__(256) void mfma_gemm_kernel(const void* __restrict__ Xv,
                                                        const unsigned short* __restrict__ blob,
                                                        unsigned short* __restrict__ Y, int n) {
    constexpr int KSTEPS = K / 32;
    const int lane = threadIdx.x & 63;
    const int wave = threadIdx.x >> 6;
    const int rowbase = blockIdx.x * 128 + wave * 32;

    const int r0 = min(rowbase +      (lane & 15), n - 1);
    const int r1 = min(rowbase + 16 + (lane & 15), n - 1);
    const int koff = (lane >> 4) * 8;

    f32x4 acc0[8], acc1[8];
#pragma unroll
    for (int c = 0; c < 8; ++c) { acc0[c] = (f32x4)0.f; acc1[c] = (f32x4)0.f; }

#pragma unroll
    for (int s = 0; s < KSTEPS; ++s) {
        bf16x8 bfr[8];
#pragma unroll
        for (int c = 0; c < 8; ++c)
            bfr[c] = *reinterpret_cast<const bf16x8*>(blob + ((size_t)((s * 8 + c) * 64 + lane)) * 8);

        bf16x8 a0, a1;
        if (IN_BF16) {
            const unsigned short* Xb = (const unsigned short*)Xv;
            a0 = *reinterpret_cast<const bf16x8*>(Xb + (size_t)r0 * K + s * 32 + koff);
            a1 = *reinterpret_cast<const bf16x8*>(Xb + (size_t)r1 * K + s * 32 + koff);
        } else {
            const float* Xf = (const float*)Xv;
            const float4* p0 = reinterpret_cast<const float4*>(Xf + (size_t)r0 * K + s * 32 + koff);
            const float4* p1 = reinterpret_cast<const float4*>(Xf + (size_t)r1 * K + s * 32 + koff);
            float4 q0 = p0[0], q1 = p0[1], q2 = p1[0], q3 = p1[1];
            a0[0] = (short)f2bf(q0.x); a0[1] = (short)f2bf(q0.y);
            a0[2] = (short)f2bf(q0.z); a0[3] = (short)f2bf(q0.w);
            a0[4] = (short)f2bf(q1.x); a0[5] = (short)f2bf(q1.y);
            a0[6] = (short)f2bf(q1.z); a0[7] = (short)f2bf(q1.w);
            a1[0] = (short)f2bf(q2.x); a1[1] = (short)f2bf(q2.y);
            a1[2] = (short)f2bf(q2.z); a1[3] = (short)f2bf(q2.w);
            a1[4] = (short)f2bf(q3.x); a1[5] = (short)f2bf(q3.y);
            a1[6] = (short)f2bf(q3.z); a1[7] = (short)f2bf(q3.w);
        }

#pragma unroll
        for (int c = 0; c < 8; ++c) {
            acc0[c] = __builtin_amdgcn_mfma_f32_16x16x32_bf16(a0, bfr[c], acc0[c], 0, 0, 0);
            acc1[c] = __builtin_amdgcn_mfma_f32_16x16x32_bf16(a1, bfr[c], acc1[c], 0, 0, 0);
        }
    }

    const int col  = lane & 15;
    const int rsub = (lane >> 4) * 4;
#pragma unroll
    for (int c = 0; c < 8; ++c) {
#pragma unroll
        for (int r = 0; r < 4; ++r) {
            int row0 = rowbase + rsub + r;
            int row1 = rowbase + 16 + rsub + r;
            if (row0 < n) Y[(size_t)row0 * HID + c * 16 + col] = f2bf(acc0[c][r]);
            if (row1 < n) Y[(size_t)row1 * HID + c * 16 + col] = f2bf(acc1[c][r]);
        }
    }
}

// ---------------- aggregation (gather, one wave per node, scalarized) -------
// h[v] = relu( dinv[v]*sum_s dinv[s]*xw[s] + dinv[v]^2*xw[v] + b )
// Wave-scalar edge loop: beg/end/s via readfirstlane -> s_loads + SALU
// addressing; per lane one u32 (2 bf16 cols), unpack lshl/and, 2 fmac.

__global__ __launch_bounds__(256) void agg_gather_kernel(const unsigned short* __restrict__ xw,
                                                         const float* __restrict__ dinv,
                                                         const int* __restrict__ row_ptr,
                                                         const int* __restrict__ csr_src,
                                                         const float* __restrict__ b,
                                                         unsigned short* __restrict__ h, int n) {
    int v = (blockIdx.x * 256 + threadIdx.x) >> 6;
    if (v >= n) return;
    int lane = threadIdx.x & 63;

    int beg = __builtin_amdgcn_readfirstlane(row_ptr[v]);
    int end = __builtin_amdgcn_readfirstlane(row_ptr[v + 1]);

    const unsigned int* xw32 = (const unsigned int*)xw;   // 2 bf16 per word
    float a0 = 0.f, a1 = 0.f;                              // cols 2*lane, 2*lane+1

    int j = beg;
    for (; j + 4 <= end; j += 4) {
        int s0 = __builtin_amdgcn_readfirstlane(csr_src[j + 0]);
        int s1 = __builtin_amdgcn_readfirstlane(csr_src[j + 1]);
        int s2 = __builtin_amdgcn_readfirstlane(csr_src[j + 2]);
        int s3 = __builtin_amdgcn_readfirstlane(csr_src[j + 3]);
        float d0 = dinv[s0], d1 = dinv[s1], d2 = dinv[s2], d3 = dinv[s3];
        unsigned int w0 = xw32[(size_t)s0 * 64 + lane];
        unsigned int w1 = xw32[(size_t)s1 * 64 + lane];
        unsigned int w2 = xw32[(size_t)s2 * 64 + lane];
        unsigned int w3 = xw32[(size_t)s3 * 64 + lane];
        a0 = fmaf(d0, lof(w0), a0); a1 = fmaf(d0, hif(w0), a1);
        a0 = fmaf(d1, lof(w1), a0); a1 = fmaf(d1, hif(w1), a1);
        a0 = fmaf(d2, lof(w2), a0); a1 = fmaf(d2, hif(w2), a1);
        a0 = fmaf(d3, lof(w3), a0); a1 = fmaf(d3, hif(w3), a1);
    }
    for (; j < end; ++j) {
        int s0 = __builtin_amdgcn_readfirstlane(csr_src[j]);
        float d0 = dinv[s0];
        unsigned int w0 = xw32[(size_t)s0 * 64 + lane];
        a0 = fmaf(d0, lof(w0), a0); a1 = fmaf(d0, hif(w0), a1);
    }

    float dv = dinv[v];
    unsigned int wv = xw32[(size_t)v * 64 + lane];
    float2 bb = *reinterpret_cast<const float2*>(b + 2 * lane);
    float s2v = dv * dv;
    float r0 = fmaxf(dv * a0 + s2v * lof(wv) + bb.x, 0.f);
    float r1 = fmaxf(dv * a1 + s2v * hif(wv) + bb.y, 0.f);
    ushort2 o;
    o.x = f2bf(r0);
    o.y = f2bf(r1);
    *reinterpret_cast<ushort2*>(h + (size_t)v * HID + 2 * lane) = o;
}

// ---------------- classifier + log_softmax ----------------

__global__ __launch_bounds__(256) void classifier_kernel(const unsigned short* __restrict__ h,
                                                         const float* __restrict__ Wc,
                                                         const float* __restrict__ bc,
                                                         float* __restrict__ out, int n) {
    __shared__ float wc0[HID], wc1[HID], bcs[2];
    if (threadIdx.x < HID) {
        wc0[threadIdx.x] = Wc[threadIdx.x * 2 + 0];
        wc1[threadIdx.x] = Wc[threadIdx.x * 2 + 1];
    }
    if (threadIdx.x < 2) bcs[threadIdx.x] = bc[threadIdx.x];
    __syncthreads();

    int i = blockIdx.x * 256 + threadIdx.x;
    if (i >= n) return;
    const ushort4* hr = reinterpret_cast<const ushort4*>(h + (size_t)i * HID);
    float l0 = 0.f, l1 = 0.f;
#pragma unroll
    for (int j4 = 0; j4 < 32; ++j4) {
        ushort4 q = hr[j4];
        float v0 = bf2f(q.x), v1 = bf2f(q.y), v2 = bf2f(q.z), v3 = bf2f(q.w);
        l0 += v0 * wc0[j4 * 4 + 0] + v1 * wc0[j4 * 4 + 1]
            + v2 * wc0[j4 * 4 + 2] + v3 * wc0[j4 * 4 + 3];
        l1 += v0 * wc1[j4 * 4 + 0] + v1 * wc1[j4 * 4 + 1]
            + v2 * wc1[j4 * 4 + 2] + v3 * wc1[j4 * 4 + 3];
    }
    l0 += bcs[0]; l1 += bcs[1];
    float m = fmaxf(l0, l1);
    float lse = m + logf(expf(l0 - m) + expf(l1 - m));
    out[i * 2 + 0] = l0 - lse;
    out[i * 2 + 1] = l1 - lse;
}

// ---------------- launch ----------------

static inline size_t align256(size_t x) { return (x + 255) & ~(size_t)255; }

extern "C" void kernel_launch(void* const* d_in, const int* in_sizes, int n_in,
                              void* d_out, int out_size, void* d_ws, size_t ws_size,
                              hipStream_t stream) {
    const float* x   = (const float*)d_in[0];
    const int*   ei  = (const int*)d_in[1];     // int32 per harness contract
    const float* W1  = (const float*)d_in[2];
    const float* b1  = (const float*)d_in[3];
    const float* W2  = (const float*)d_in[4];
    const float* b2  = (const float*)d_in[5];
    const float* W3  = (const float*)d_in[6];
    const float* b3  = (const float*)d_in[7];
    const float* Wc  = (const float*)d_in[8];
    const float* bc  = (const float*)d_in[9];
    float*       out = (float*)d_out;

    const int* src = ei;             // edge_index[0,:]
    const int* dst = ei + N_EDGES;   // edge_index[1,:]

    // workspace layout
    size_t off = 0;
    size_t o_dinv    = off; off = align256(off + (size_t)N_NODES * 4);
    size_t o_deg     = off; off = align256(off + (size_t)N_NODES * 4);
    size_t o_rowptr  = off; off = align256(off + (size_t)(N_NODES + 1) * 4);
    size_t o_bsums   = off; off = align256(off + (size_t)N_SCAN_BLOCKS * 4);
    size_t o_bcnt    = off; off = align256(off + (size_t)NB * 4);
    size_t o_bbase   = off; off = align256(off + (size_t)(NB + 1) * 4);
    size_t o_gfill   = off; off = align256(off + (size_t)NB * 4);
    size_t o_csr     = off; off = align256(off + (size_t)N_EDGES * 4);
    size_t o_stgs    = off; off = align256(off + (size_t)N_EDGES * 4);
    size_t o_stgd    = off; off = align256(off + (size_t)N_EDGES * 4);
    size_t o_blob1   = off; off = align256(off + (size_t)(F_IN / 32) * 8 * 64 * 8 * 2);
    size_t o_blob2   = off; off = align256(off + (size_t)(HID / 32) * 8 * 64 * 8 * 2);
    size_t o_blob3   = off; off = align256(off + (size_t)(HID / 32) * 8 * 64 * 8 * 2);
    size_t o_bufA    = off; off = align256(off + (size_t)N_NODES * HID * 2);
    size_t o_bufB    = off; off = align256(off + (size_t)N_NODES * HID * 2);
    size_t need = off;                           // ~72 MB

    const int nThr = 256;
    const int gOut = (out_size + nThr - 1) / nThr;
    if (ws_size < need) {
        zero_f_kernel<<<gOut, nThr, 0, stream>>>(out, out_size);
        return;
    }

    char* ws = (char*)d_ws;
    float*          dinv    = (float*)(ws + o_dinv);
    int*            deg     = (int*)(ws + o_deg);
    int*            row_ptr = (int*)(ws + o_rowptr);
    int*            bsums   = (int*)(ws + o_bsums);
    int*            bcnt    = (int*)(ws + o_bcnt);
    int*            bbase   = (int*)(ws + o_bbase);
    int*            gfill   = (int*)(ws + o_gfill);
    int*            csr_src = (int*)(ws + o_csr);
    int*            stg_src = (int*)(ws + o_stgs);
    int*            stg_dst = (int*)(ws + o_stgd);
    unsigned short* blob1   = (unsigned short*)(ws + o_blob1);
    unsigned short* blob2   = (unsigned short*)(ws + o_blob2);
    unsigned short* blob3   = (unsigned short*)(ws + o_blob3);
    unsigned short* bufA    = (unsigned short*)(ws + o_bufA);   // xw (bf16)
    unsigned short* bufB    = (unsigned short*)(ws + o_bufB);   // h  (bf16)

    const int gN = (N_NODES + nThr - 1) / nThr;
    const int gW = (N_NODES * 64 + nThr - 1) / nThr;
    const int gG = (N_NODES + 127) / 128;

    // ---- bucketed CSR build ----
    zero_int_kernel<<<(NB + 255) / 256, nThr, 0, stream>>>(bcnt, NB);
    zero_int_kernel<<<(NB + 255) / 256, nThr, 0, stream>>>(gfill, NB);
    bucket_count_kernel<<<N_CHUNKS, nThr, 0, stream>>>(dst, bcnt, N_EDGES);
    scan_bucket_kernel<<<1, 512, 0, stream>>>(bcnt, bbase);
    stage_kernel<<<N_CHUNKS, nThr, 0, stream>>>(src, dst, bbase, gfill,
                                                stg_src, stg_dst, N_EDGES);
    bucket_deg_kernel<<<NB, nThr, 0, stream>>>(stg_dst, bbase, deg, N_NODES);
    dinv_kernel<<<gN, nThr, 0, stream>>>(deg, dinv, N_NODES);
    scan_reduce_kernel<<<N_SCAN_BLOCKS, nThr, 0, stream>>>(deg, N_NODES, bsums);
    scan_small_kernel<<<1, 128, 0, stream>>>(bsums, N_SCAN_BLOCKS);
    scan_final_kernel<<<N_SCAN_BLOCKS, nThr, 0, stream>>>(deg, N_NODES, bsums, row_ptr, N_EDGES);
    bucket_fill_kernel<<<NB, nThr, 0, stream>>>(stg_src, stg_dst, bbase, row_ptr, csr_src);

    // ---- W blobs ----
    prep_blob_kernel<F_IN><<<16, nThr, 0, stream>>>(W1, blob1);
    prep_blob_kernel<HID><<<8, nThr, 0, stream>>>(W2, blob2);
    prep_blob_kernel<HID><<<8, nThr, 0, stream>>>(W3, blob3);

    // ---- layers ----
    mfma_gemm_kernel<F_IN, false><<<gG, nThr, 0, stream>>>(x, blob1, bufA, N_NODES);
    agg_gather_kernel<<<gW, nThr, 0, stream>>>(bufA, dinv, row_ptr, csr_src, b1, bufB, N_NODES);

    mfma_gemm_kernel<HID, true><<<gG, nThr, 0, stream>>>(bufB, blob2, bufA, N_NODES);
    agg_gather_kernel<<<gW, nThr, 0, stream>>>(bufA, dinv, row_ptr, csr_src, b2, bufB, N_NODES);

    mfma_gemm_kernel<HID, true><<<gG, nThr, 0, stream>>>(bufB, blob3, bufA, N_NODES);
    agg_gather_kernel<<<gW, nThr, 0, stream>>>(bufA, dinv, row_ptr, csr_src, b3, bufB, N_NODES);

    // ---- classifier ----
    classifier_kernel<<<gN, nThr, 0, stream>>>(bufB, Wc, bc, out, N_NODES);
}